// Round 6
// baseline (545.247 us; speedup 1.0000x reference)
//
#include <hip/hip_runtime.h>

#define N_NODES 100000
#define E_EDGES 3200000
#define F_IN    512
#define C_OUT   64
#define NB      782      // buckets: node >> 7 (128 nodes per bucket)
#define CAP     5120     // bucket capacity (mean 4092, sigma 64 -> 16 sigma)
#define TILE    4096     // edges per block in P2 (782 blocks -> ~3/CU occupancy)
#define NTILE   782      // ceil(E / TILE)

typedef __bf16 bf16x8 __attribute__((ext_vector_type(8)));
typedef float  f32x4  __attribute__((ext_vector_type(4)));
typedef float  f32x2  __attribute__((ext_vector_type(2)));

// fp32 -> bf16 (round-to-nearest-even), bit-level
static __device__ __forceinline__ unsigned short f2bf(float f) {
    unsigned int u = __float_as_uint(f);
    u = (u + 0x7FFFu + ((u >> 16) & 1u)) >> 16;
    return (unsigned short)u;
}
// bf16 bits -> fp32 (exact)
static __device__ __forceinline__ float bf2f(unsigned short b) {
    return __uint_as_float(((unsigned int)b) << 16);
}
// fp32 -> fp8 e4m3 (OCP on gfx950), single byte via HW convert
static __device__ __forceinline__ unsigned char f32_to_fp8(float v) {
    return (unsigned char)(__builtin_amdgcn_cvt_pk_fp8_f32(v, v, 0, false) & 0xFF);
}
// 2 packed fp8 -> 2 fp32 via HW convert (same HW format as encode)
static __device__ __forceinline__ f32x2 fp8x2_to_f32(unsigned short u) {
    return __builtin_amdgcn_cvt_pk_f32_fp8((int)(unsigned int)u, false);
}

// ---------------------------------------------------------------------------
// zero/prep: out-degree array + bucket cursors + W fp32->bf16 (64KB, so the
// GEMM can read B-fragments straight from L2 and keep LDS tiny).
// ---------------------------------------------------------------------------
__global__ __launch_bounds__(512) void zero_kernel(const float* __restrict__ W,
                                                   unsigned short* __restrict__ Wb,
                                                   int* __restrict__ deg_src,
                                                   int* __restrict__ cursor_d) {
    int i = blockIdx.x * 512 + threadIdx.x;
    if (i < N_NODES) deg_src[i] = 0;
    if (i < NB) cursor_d[i] = 0;
    if (i < C_OUT * F_IN) Wb[i] = f2bf(W[i]);
}

// ---------------------------------------------------------------------------
// P2: two-pass dst-partition into fixed-capacity bucket regions + global
// out-degree atomics. TILE=4096 -> 782 blocks (~3/CU): round-5 counters
// showed 15% occupancy at 196 blocks was the binder (VALU 1.1%, HBM 12.6%).
//   tmp[b*CAP..] : u32 (dst&127)<<24 | src
// ---------------------------------------------------------------------------
__global__ __launch_bounds__(512) void p2_part(const int* __restrict__ src,
                                               const int* __restrict__ dst,
                                               int* __restrict__ cursor_d,
                                               int* __restrict__ deg_src,
                                               unsigned int* __restrict__ tmp) {
    __shared__ int cd[NB];
    __shared__ int bd[NB];
    int t = threadIdx.x;
    for (int j = t; j < NB; j += 512) cd[j] = 0;
    __syncthreads();
    int tb = blockIdx.x * TILE;
    // --- pass A: count ---
    #pragma unroll 8
    for (int i = 0; i < 8; ++i) {
        int e = tb + i * 512 + t;
        if (e < E_EDGES) {
            atomicAdd(&cd[dst[e] >> 7], 1);
            atomicAdd(&deg_src[src[e]], 1);
        }
    }
    __syncthreads();
    // --- reserve contiguous runs ---
    for (int j = t; j < NB; j += 512) {
        int c = cd[j];
        bd[j] = j * CAP + (c ? atomicAdd(&cursor_d[j], c) : 0);
        cd[j] = 0;
    }
    __syncthreads();
    // --- pass B: write (re-read src/dst, L2-hot) ---
    #pragma unroll 8
    for (int i = 0; i < 8; ++i) {
        int e = tb + i * 512 + t;
        if (e < E_EDGES) {
            int s = src[e], d = dst[e];
            int db = d >> 7;
            int p = atomicAdd(&cd[db], 1);
            tmp[bd[db] + p] = ((unsigned int)(d & 127) << 24) | (unsigned int)s;
        }
    }
}

// ---------------------------------------------------------------------------
// GEMM v2 (bf16 MFMA), 256 rows/block, 512 threads (8 waves x 2 M-tiles).
// W is NOT in LDS (B-fragments read from the 64KB L2-hot Wb array); LDS holds
// only a single-buffered bf16 A-tile [256][32] (16KB). Staging is reg-based
// with early-issued loads (T14 split): issue next tile's 4x dwordx4 before
// the MFMAs, convert+ds_write after the barrier. ~90-110 VGPR + 16KB LDS ->
// 16 waves/CU (vs 8 before): ~64KB of A in flight per CU -> BW-paced.
// Writes h0b (bf16, channel-ordered) AND h8 (fp8, norm_src pre-folded,
// 2-way interleaved: byte 2i = ch i, byte 2i+1 = ch i+32).
// ---------------------------------------------------------------------------
__global__ __launch_bounds__(512, 4) void gemm_kernel(const float* __restrict__ A,
                                                      const unsigned short* __restrict__ Wb,
                                                      const float* __restrict__ bias,
                                                      const int* __restrict__ deg_src,
                                                      unsigned short* __restrict__ h0b,
                                                      unsigned char* __restrict__ h8) {
    __shared__ unsigned short Al[256 * 32];   // 16384 B, [row][k] bf16, linear

    const int tid  = threadIdx.x;
    const int w    = tid >> 6;       // wave 0..7
    const int lane = tid & 63;
    const int cl   = lane & 15;
    const int quad = lane >> 4;
    const int row0 = blockIdx.x * 256;

    // staging role: thread covers row tid>>1, cols (tid&1)*16 .. +16 (fp32)
    const int srow  = tid >> 1;
    const int shalf = tid & 1;
    int grow = row0 + srow;
    if (grow >= N_NODES) grow = N_NODES - 1;   // duplicate reads, outputs masked
    const float* gsrc = A + (size_t)grow * F_IN + shalf * 16;
    unsigned short* sdst = &Al[srow * 32 + shalf * 16];

    // fragment read base: wave owns rows [w*32, w*32+32), mt in {0,1}
    const int frow = w * 32 + cl;
    const unsigned short* fr0 = &Al[(frow +  0) * 32 + quad * 8];
    const unsigned short* fr1 = &Al[(frow + 16) * 32 + quad * 8];

    const unsigned short* wp0 = Wb + (cl +  0) * F_IN + quad * 8;
    const unsigned short* wp1 = Wb + (cl + 16) * F_IN + quad * 8;
    const unsigned short* wp2 = Wb + (cl + 32) * F_IN + quad * 8;
    const unsigned short* wp3 = Wb + (cl + 48) * F_IN + quad * 8;

    f32x4 acc0[2], acc1[2], acc2[2], acc3[2];
    #pragma unroll
    for (int mt = 0; mt < 2; ++mt) {
        acc0[mt] = (f32x4){0.f, 0.f, 0.f, 0.f};
        acc1[mt] = (f32x4){0.f, 0.f, 0.f, 0.f};
        acc2[mt] = (f32x4){0.f, 0.f, 0.f, 0.f};
        acc3[mt] = (f32x4){0.f, 0.f, 0.f, 0.f};
    }

    // prologue: stage tile 0
    {
        float4 s0 = *reinterpret_cast<const float4*>(gsrc + 0);
        float4 s1 = *reinterpret_cast<const float4*>(gsrc + 4);
        float4 s2 = *reinterpret_cast<const float4*>(gsrc + 8);
        float4 s3 = *reinterpret_cast<const float4*>(gsrc + 12);
        bf16x8 lo, hi;
        lo[0] = (__bf16)s0.x; lo[1] = (__bf16)s0.y; lo[2] = (__bf16)s0.z; lo[3] = (__bf16)s0.w;
        lo[4] = (__bf16)s1.x; lo[5] = (__bf16)s1.y; lo[6] = (__bf16)s1.z; lo[7] = (__bf16)s1.w;
        hi[0] = (__bf16)s2.x; hi[1] = (__bf16)s2.y; hi[2] = (__bf16)s2.z; hi[3] = (__bf16)s2.w;
        hi[4] = (__bf16)s3.x; hi[5] = (__bf16)s3.y; hi[6] = (__bf16)s3.z; hi[7] = (__bf16)s3.w;
        *reinterpret_cast<bf16x8*>(sdst)     = lo;
        *reinterpret_cast<bf16x8*>(sdst + 8) = hi;
    }
    __syncthreads();

    for (int k0 = 0; k0 < F_IN; k0 += 32) {
        // issue next tile's loads EARLY (hide HBM under MFMAs + barrier)
        float4 n0, n1, n2, n3;
        const bool more = (k0 + 32 < F_IN);
        if (more) {
            const float* g = gsrc + k0 + 32;
            n0 = *reinterpret_cast<const float4*>(g + 0);
            n1 = *reinterpret_cast<const float4*>(g + 4);
            n2 = *reinterpret_cast<const float4*>(g + 8);
            n3 = *reinterpret_cast<const float4*>(g + 12);
        }

        bf16x8 a0 = *reinterpret_cast<const bf16x8*>(fr0);
        bf16x8 a1 = *reinterpret_cast<const bf16x8*>(fr1);
        bf16x8 b0 = *reinterpret_cast<const bf16x8*>(wp0 + k0);
        bf16x8 b1 = *reinterpret_cast<const bf16x8*>(wp1 + k0);
        bf16x8 b2 = *reinterpret_cast<const bf16x8*>(wp2 + k0);
        bf16x8 b3 = *reinterpret_cast<const bf16x8*>(wp3 + k0);

        acc0[0] = __builtin_amdgcn_mfma_f32_16x16x32_bf16(a0, b0, acc0[0], 0, 0, 0);
        acc1[0] = __builtin_amdgcn_mfma_f32_16x16x32_bf16(a0, b1, acc1[0], 0, 0, 0);
        acc2[0] = __builtin_amdgcn_mfma_f32_16x16x32_bf16(a0, b2, acc2[0], 0, 0, 0);
        acc3[0] = __builtin_amdgcn_mfma_f32_16x16x32_bf16(a0, b3, acc3[0], 0, 0, 0);
        acc0[1] = __builtin_amdgcn_mfma_f32_16x16x32_bf16(a1, b0, acc0[1], 0, 0, 0);
        acc1[1] = __builtin_amdgcn_mfma_f32_16x16x32_bf16(a1, b1, acc1[1], 0, 0, 0);
        acc2[1] = __builtin_amdgcn_mfma_f32_16x16x32_bf16(a1, b2, acc2[1], 0, 0, 0);
        acc3[1] = __builtin_amdgcn_mfma_f32_16x16x32_bf16(a1, b3, acc3[1], 0, 0, 0);

        __syncthreads();          // all reads of Al for this step are done
        if (more) {
            bf16x8 lo, hi;
            lo[0] = (__bf16)n0.x; lo[1] = (__bf16)n0.y; lo[2] = (__bf16)n0.z; lo[3] = (__bf16)n0.w;
            lo[4] = (__bf16)n1.x; lo[5] = (__bf16)n1.y; lo[6] = (__bf16)n1.z; lo[7] = (__bf16)n1.w;
            hi[0] = (__bf16)n2.x; hi[1] = (__bf16)n2.y; hi[2] = (__bf16)n2.z; hi[3] = (__bf16)n2.w;
            hi[4] = (__bf16)n3.x; hi[5] = (__bf16)n3.y; hi[6] = (__bf16)n3.z; hi[7] = (__bf16)n3.w;
            *reinterpret_cast<bf16x8*>(sdst)     = lo;
            *reinterpret_cast<bf16x8*>(sdst + 8) = hi;
        }
        __syncthreads();          // Al ready for next step
    }

    float bias0 = bias[cl +  0];
    float bias1 = bias[cl + 16];
    float bias2 = bias[cl + 32];
    float bias3 = bias[cl + 48];
    #pragma unroll
    for (int mt = 0; mt < 2; ++mt) {
        #pragma unroll
        for (int r = 0; r < 4; ++r) {
            int row = row0 + w * 32 + mt * 16 + quad * 4 + r;
            if (row < N_NODES) {
                float v0 = acc0[mt][r] + bias0;   // channel cl
                float v1 = acc1[mt][r] + bias1;   // channel cl+16
                float v2 = acc2[mt][r] + bias2;   // channel cl+32
                float v3 = acc3[mt][r] + bias3;   // channel cl+48
                unsigned short* o = &h0b[(size_t)row * C_OUT + cl];
                o[ 0] = f2bf(v0);
                o[16] = f2bf(v1);
                o[32] = f2bf(v2);
                o[48] = f2bf(v3);
                int dg = deg_src[row];
                float ns = rsqrtf((float)(dg < 1 ? 1 : dg));
                unsigned char* o8 = &h8[(size_t)row * C_OUT];
                // interleaved: byte 2i = ch i, byte 2i+1 = ch i+32
                o8[2 * cl     ] = f32_to_fp8(v0 * ns);   // ch cl
                o8[2 * cl + 32] = f32_to_fp8(v1 * ns);   // ch cl+16 -> byte 2(cl+16)
                o8[2 * cl +  1] = f32_to_fp8(v2 * ns);   // ch cl+32
                o8[2 * cl + 33] = f32_to_fp8(v3 * ns);   // ch cl+48
            }
        }
    }
}

// ---------------------------------------------------------------------------
// agg (unchanged from round 5, proven <162us): block b owns 128 nodes.
// CSR built in LDS with int atomics + prefix scan + cursor scatter, then
// per-wave register gather (16 edges in flight, 32 lanes x 2 channels).
// ---------------------------------------------------------------------------
__global__ __launch_bounds__(512, 4) void agg_kernel(const unsigned int* __restrict__ tmp,
                                                     const int* __restrict__ cursor_d,
                                                     const unsigned char* __restrict__ h8,
                                                     const unsigned short* __restrict__ h0b,
                                                     float* __restrict__ out) {
    __shared__ int es[CAP];        // 20480 B: within-block CSR edge srcs
    __shared__ int cnt[128];
    __shared__ int off[128];
    __shared__ int lc[128];
    __shared__ int sscan[128];

    int t = threadIdx.x;
    int b = blockIdx.x;

    if (t < 128) { cnt[t] = 0; lc[t] = 0; }
    __syncthreads();

    int nE = cursor_d[b];
    if (nE > CAP) nE = CAP;
    const unsigned int* te = tmp + (size_t)b * CAP;

    // pass 1: in-degree histogram (int LDS atomics)
    for (int e = t; e < nE; e += 512)
        atomicAdd(&cnt[te[e] >> 24], 1);
    __syncthreads();

    // exclusive prefix scan over 128 counters
    if (t < 128) sscan[t] = cnt[t];
    __syncthreads();
    #pragma unroll
    for (int o = 1; o < 128; o <<= 1) {
        int add = (t < 128 && t >= o) ? sscan[t - o] : 0;
        __syncthreads();
        if (t < 128) sscan[t] += add;
        __syncthreads();
    }
    if (t < 128) off[t] = sscan[t] - cnt[t];
    __syncthreads();

    // pass 2: scatter edge srcs into LDS CSR
    for (int e = t; e < nE; e += 512) {
        unsigned int v = te[e];
        int dl = v >> 24;
        int p = atomicAdd(&lc[dl], 1);
        es[off[dl] + p] = (int)(v & 0xFFFFFFu);
    }
    __syncthreads();

    // per-wave register-accumulating gather: wave w owns nodes [16w, 16w+16)
    int w    = t >> 6;
    int lane = t & 63;
    int half = lane >> 5;          // edge slot parity
    int c2   = lane & 31;          // channel pair (c2, c2+32)
    const unsigned short* h8p = reinterpret_cast<const unsigned short*>(h8); // row stride 32

    for (int r = 0; r < 16; ++r) {
        int nl   = (w << 4) + r;
        int node = (b << 7) + nl;
        int beg  = off[nl];
        int deg  = cnt[nl];
        int end  = beg + deg;
        float ax = 0.f, ay = 0.f;

        int base = beg;
        for (; base + 16 <= end; base += 16) {
            int e0 = base + half;
            int s0 = es[e0 +  0];
            int s1 = es[e0 +  2];
            int s2 = es[e0 +  4];
            int s3 = es[e0 +  6];
            int s4 = es[e0 +  8];
            int s5 = es[e0 + 10];
            int s6 = es[e0 + 12];
            int s7 = es[e0 + 14];
            unsigned short u0 = h8p[s0 * 32 + c2];
            unsigned short u1 = h8p[s1 * 32 + c2];
            unsigned short u2 = h8p[s2 * 32 + c2];
            unsigned short u3 = h8p[s3 * 32 + c2];
            unsigned short u4 = h8p[s4 * 32 + c2];
            unsigned short u5 = h8p[s5 * 32 + c2];
            unsigned short u6 = h8p[s6 * 32 + c2];
            unsigned short u7 = h8p[s7 * 32 + c2];
            f32x2 f0 = fp8x2_to_f32(u0);
            f32x2 f1 = fp8x2_to_f32(u1);
            f32x2 f2 = fp8x2_to_f32(u2);
            f32x2 f3 = fp8x2_to_f32(u3);
            f32x2 f4 = fp8x2_to_f32(u4);
            f32x2 f5 = fp8x2_to_f32(u5);
            f32x2 f6 = fp8x2_to_f32(u6);
            f32x2 f7 = fp8x2_to_f32(u7);
            ax += (f0[0] + f1[0]) + (f2[0] + f3[0]) + (f4[0] + f5[0]) + (f6[0] + f7[0]);
            ay += (f0[1] + f1[1]) + (f2[1] + f3[1]) + (f4[1] + f5[1]) + (f6[1] + f7[1]);
        }
        for (int e = base + half; e < end; e += 2) {
            int s = es[e];
            f32x2 f = fp8x2_to_f32(h8p[s * 32 + c2]);
            ax += f[0];
            ay += f[1];
        }

        ax += __shfl(ax, lane ^ 32, 64);
        ay += __shfl(ay, lane ^ 32, 64);

        if (half == 0 && node < N_NODES) {
            float nd = rsqrtf((float)(deg < 1 ? 1 : deg));
            float hx = bf2f(h0b[(size_t)node * C_OUT + c2]);
            float hy = bf2f(h0b[(size_t)node * C_OUT + c2 + 32]);
            out[(size_t)node * C_OUT + c2]      = 0.8f * nd * ax + 0.2f * hx;
            out[(size_t)node * C_OUT + c2 + 32] = 0.8f * nd * ay + 0.2f * hy;
        }
    }
}

// ---------------------------------------------------------------------------
extern "C" void kernel_launch(void* const* d_in, const int* in_sizes, int n_in,
                              void* d_out, int out_size, void* d_ws, size_t ws_size,
                              hipStream_t stream) {
    const float* in_feat = (const float*)d_in[0];   // [N, 512]
    const float* W       = (const float*)d_in[1];   // [64, 512]
    const float* bias    = (const float*)d_in[2];   // [64]
    const int*   src     = (const int*)d_in[3];     // [E]
    const int*   dst     = (const int*)d_in[4];     // [E]
    float* out = (float*)d_out;                     // [N, 64]

    // workspace layout (no aliasing; ~36MB of ~800MB):
    char* p = (char*)d_ws;
    unsigned short* h0b = (unsigned short*)p;  p += (size_t)N_NODES * C_OUT * 2;   // 12.8MB
    unsigned char*  h8  = (unsigned char*)p;   p += (size_t)N_NODES * C_OUT;       // 6.4MB
    unsigned int*   tmp = (unsigned int*)p;    p += (size_t)NB * CAP * 4;          // 16MB
    int*   deg_src  = (int*)p;                 p += (size_t)N_NODES * 4;           // 0.4MB
    int*   cursor_d = (int*)p;                 p += (size_t)NB * 4;
    unsigned short* Wb = (unsigned short*)p;   p += (size_t)C_OUT * F_IN * 2;      // 64KB

    zero_kernel<<<(N_NODES + 511) / 512, 512, 0, stream>>>(W, Wb, deg_src, cursor_d);
    p2_part<<<NTILE, 512, 0, stream>>>(src, dst, cursor_d, deg_src, tmp);
    gemm_kernel<<<(N_NODES + 255) / 256, 512, 0, stream>>>(in_feat, Wb, bias,
                                                           deg_src, h0b, h8);
    agg_kernel<<<NB, 512, 0, stream>>>(tmp, cursor_d, h8, h0b, out);
}

// Round 7
// 541.281 us; speedup vs baseline: 1.0073x; 1.0073x over previous
//
#include <hip/hip_runtime.h>

#define N_NODES 100000
#define E_EDGES 3200000
#define F_IN    512
#define C_OUT   64
#define NB      782      // buckets: node >> 7 (128 nodes per bucket)
#define CAP     5120     // bucket capacity (mean 4092, sigma 64 -> 16 sigma)
#define TILE    16384    // edges per block in P2 (196 blocks: measured fastest)
#define NTILE   196      // ceil(E / TILE)

typedef __bf16 bf16x8 __attribute__((ext_vector_type(8)));
typedef float  f32x4  __attribute__((ext_vector_type(4)));
typedef float  f32x2  __attribute__((ext_vector_type(2)));

// fp32 -> bf16 (round-to-nearest-even), bit-level
static __device__ __forceinline__ unsigned short f2bf(float f) {
    unsigned int u = __float_as_uint(f);
    u = (u + 0x7FFFu + ((u >> 16) & 1u)) >> 16;
    return (unsigned short)u;
}
// bf16 bits -> fp32 (exact)
static __device__ __forceinline__ float bf2f(unsigned short b) {
    return __uint_as_float(((unsigned int)b) << 16);
}
// fp32 -> fp8 e4m3 (OCP on gfx950), single byte via HW convert
static __device__ __forceinline__ unsigned char f32_to_fp8(float v) {
    return (unsigned char)(__builtin_amdgcn_cvt_pk_fp8_f32(v, v, 0, false) & 0xFF);
}
// 2 packed fp8 -> 2 fp32 via HW convert (same HW format as encode)
static __device__ __forceinline__ f32x2 fp8x2_to_f32(unsigned short u) {
    return __builtin_amdgcn_cvt_pk_f32_fp8((int)(unsigned int)u, false);
}

// ---------------------------------------------------------------------------
// zero/prep: out-degree array + bucket cursors + W fp32->bf16 (64KB, so the
// GEMM can read B-fragments straight from L2).
// ---------------------------------------------------------------------------
__global__ __launch_bounds__(512) void zero_kernel(const float* __restrict__ W,
                                                   unsigned short* __restrict__ Wb,
                                                   int* __restrict__ deg_src,
                                                   int* __restrict__ cursor_d) {
    int i = blockIdx.x * 512 + threadIdx.x;
    if (i < N_NODES) deg_src[i] = 0;
    if (i < NB) cursor_d[i] = 0;
    if (i < C_OUT * F_IN) Wb[i] = f2bf(W[i]);
}

// ---------------------------------------------------------------------------
// P2: two-pass dst-partition into fixed-capacity bucket regions + global
// out-degree atomics. TILE=16384/196 blocks (measured 162us; 782 blocks with
// 60% occupancy was SLOWER at 172 -> serialization-bound, not wave-starved).
//   tmp[b*CAP..] : u32 (dst&127)<<24 | src
// ---------------------------------------------------------------------------
__global__ __launch_bounds__(512) void p2_part(const int* __restrict__ src,
                                               const int* __restrict__ dst,
                                               int* __restrict__ cursor_d,
                                               int* __restrict__ deg_src,
                                               unsigned int* __restrict__ tmp) {
    __shared__ int cd[NB];
    __shared__ int bd[NB];
    int t = threadIdx.x;
    for (int j = t; j < NB; j += 512) cd[j] = 0;
    __syncthreads();
    int tb = blockIdx.x * TILE;
    // --- pass A: count ---
    #pragma unroll 4
    for (int i = 0; i < 32; ++i) {
        int e = tb + i * 512 + t;
        if (e < E_EDGES) {
            atomicAdd(&cd[dst[e] >> 7], 1);
            atomicAdd(&deg_src[src[e]], 1);
        }
    }
    __syncthreads();
    // --- reserve contiguous runs ---
    for (int j = t; j < NB; j += 512) {
        int c = cd[j];
        bd[j] = j * CAP + (c ? atomicAdd(&cursor_d[j], c) : 0);
        cd[j] = 0;
    }
    __syncthreads();
    // --- pass B: write (re-read src/dst, L2-hot) ---
    #pragma unroll 4
    for (int i = 0; i < 32; ++i) {
        int e = tb + i * 512 + t;
        if (e < E_EDGES) {
            int s = src[e], d = dst[e];
            int db = d >> 7;
            int p = atomicAdd(&cd[db], 1);
            tmp[bd[db] + p] = ((unsigned int)(d & 127) << 24) | (unsigned int)s;
        }
    }
}

// ---------------------------------------------------------------------------
// GEMM v3 (bf16 MFMA), NO LDS, NO barriers. Key insight: each wave consumes
// only its OWN 32 rows of A -> LDS staging shares nothing, it only reshapes
// coalescing. Direct per-lane fragment loads are already line-coalesced
// (16 rows x 128B per wave-instr). k-loop is barrier-free -> compiler
// software-pipelines loads across k-steps (loads feed MFMAs, the pattern it
// provably handles; unroll 2 for cross-step MLP). B-fragments from 64KB
// L2-resident Wb. 512 thr = 8 waves x 2 M-tiles = 256 rows/block.
// Writes h0b (bf16) AND h8 (fp8, norm_src pre-folded, 2-way interleaved:
// byte 2i = ch i, byte 2i+1 = ch i+32).
// ---------------------------------------------------------------------------
__global__ __launch_bounds__(512) void gemm_kernel(const float* __restrict__ A,
                                                   const unsigned short* __restrict__ Wb,
                                                   const float* __restrict__ bias,
                                                   const int* __restrict__ deg_src,
                                                   unsigned short* __restrict__ h0b,
                                                   unsigned char* __restrict__ h8) {
    const int tid  = threadIdx.x;
    const int w    = tid >> 6;       // wave 0..7
    const int lane = tid & 63;
    const int cl   = lane & 15;
    const int quad = lane >> 4;
    const int row0 = blockIdx.x * 256;

    int r0 = row0 + w * 32 + cl;         // mt=0 row
    int r1 = r0 + 16;                    // mt=1 row
    if (r0 >= N_NODES) r0 = N_NODES - 1; // duplicate reads, outputs masked
    if (r1 >= N_NODES) r1 = N_NODES - 1;
    const float* ap0 = A + (size_t)r0 * F_IN + quad * 8;
    const float* ap1 = A + (size_t)r1 * F_IN + quad * 8;

    const unsigned short* wp0 = Wb + (cl +  0) * F_IN + quad * 8;
    const unsigned short* wp1 = Wb + (cl + 16) * F_IN + quad * 8;
    const unsigned short* wp2 = Wb + (cl + 32) * F_IN + quad * 8;
    const unsigned short* wp3 = Wb + (cl + 48) * F_IN + quad * 8;

    f32x4 acc0[2], acc1[2], acc2[2], acc3[2];
    #pragma unroll
    for (int mt = 0; mt < 2; ++mt) {
        acc0[mt] = (f32x4){0.f, 0.f, 0.f, 0.f};
        acc1[mt] = (f32x4){0.f, 0.f, 0.f, 0.f};
        acc2[mt] = (f32x4){0.f, 0.f, 0.f, 0.f};
        acc3[mt] = (f32x4){0.f, 0.f, 0.f, 0.f};
    }

    #pragma unroll 2
    for (int k0 = 0; k0 < F_IN; k0 += 32) {
        float4 p0 = *reinterpret_cast<const float4*>(ap0 + k0);
        float4 q0 = *reinterpret_cast<const float4*>(ap0 + k0 + 4);
        float4 p1 = *reinterpret_cast<const float4*>(ap1 + k0);
        float4 q1 = *reinterpret_cast<const float4*>(ap1 + k0 + 4);
        bf16x8 b0 = *reinterpret_cast<const bf16x8*>(wp0 + k0);
        bf16x8 b1 = *reinterpret_cast<const bf16x8*>(wp1 + k0);
        bf16x8 b2 = *reinterpret_cast<const bf16x8*>(wp2 + k0);
        bf16x8 b3 = *reinterpret_cast<const bf16x8*>(wp3 + k0);

        bf16x8 a0, a1;
        a0[0] = (__bf16)p0.x; a0[1] = (__bf16)p0.y; a0[2] = (__bf16)p0.z; a0[3] = (__bf16)p0.w;
        a0[4] = (__bf16)q0.x; a0[5] = (__bf16)q0.y; a0[6] = (__bf16)q0.z; a0[7] = (__bf16)q0.w;
        a1[0] = (__bf16)p1.x; a1[1] = (__bf16)p1.y; a1[2] = (__bf16)p1.z; a1[3] = (__bf16)p1.w;
        a1[4] = (__bf16)q1.x; a1[5] = (__bf16)q1.y; a1[6] = (__bf16)q1.z; a1[7] = (__bf16)q1.w;

        acc0[0] = __builtin_amdgcn_mfma_f32_16x16x32_bf16(a0, b0, acc0[0], 0, 0, 0);
        acc1[0] = __builtin_amdgcn_mfma_f32_16x16x32_bf16(a0, b1, acc1[0], 0, 0, 0);
        acc2[0] = __builtin_amdgcn_mfma_f32_16x16x32_bf16(a0, b2, acc2[0], 0, 0, 0);
        acc3[0] = __builtin_amdgcn_mfma_f32_16x16x32_bf16(a0, b3, acc3[0], 0, 0, 0);
        acc0[1] = __builtin_amdgcn_mfma_f32_16x16x32_bf16(a1, b0, acc0[1], 0, 0, 0);
        acc1[1] = __builtin_amdgcn_mfma_f32_16x16x32_bf16(a1, b1, acc1[1], 0, 0, 0);
        acc2[1] = __builtin_amdgcn_mfma_f32_16x16x32_bf16(a1, b2, acc2[1], 0, 0, 0);
        acc3[1] = __builtin_amdgcn_mfma_f32_16x16x32_bf16(a1, b3, acc3[1], 0, 0, 0);
    }

    float bias0 = bias[cl +  0];
    float bias1 = bias[cl + 16];
    float bias2 = bias[cl + 32];
    float bias3 = bias[cl + 48];
    #pragma unroll
    for (int mt = 0; mt < 2; ++mt) {
        #pragma unroll
        for (int r = 0; r < 4; ++r) {
            int row = row0 + w * 32 + mt * 16 + quad * 4 + r;
            if (row < N_NODES) {
                float v0 = acc0[mt][r] + bias0;   // channel cl
                float v1 = acc1[mt][r] + bias1;   // channel cl+16
                float v2 = acc2[mt][r] + bias2;   // channel cl+32
                float v3 = acc3[mt][r] + bias3;   // channel cl+48
                unsigned short* o = &h0b[(size_t)row * C_OUT + cl];
                o[ 0] = f2bf(v0);
                o[16] = f2bf(v1);
                o[32] = f2bf(v2);
                o[48] = f2bf(v3);
                int dg = deg_src[row];
                float ns = rsqrtf((float)(dg < 1 ? 1 : dg));
                unsigned char* o8 = &h8[(size_t)row * C_OUT];
                // interleaved: byte 2i = ch i, byte 2i+1 = ch i+32
                o8[2 * cl     ] = f32_to_fp8(v0 * ns);   // ch cl
                o8[2 * cl + 32] = f32_to_fp8(v1 * ns);   // ch cl+16 -> byte 2(cl+16)
                o8[2 * cl +  1] = f32_to_fp8(v2 * ns);   // ch cl+32
                o8[2 * cl + 33] = f32_to_fp8(v3 * ns);   // ch cl+48
            }
        }
    }
}

// ---------------------------------------------------------------------------
// agg (unchanged, proven <171us): block b owns 128 nodes. CSR built in LDS
// with int atomics + prefix scan + cursor scatter, then per-wave register
// gather (16 edges in flight, 32 lanes x 2 channels via interleaved h8).
// ---------------------------------------------------------------------------
__global__ __launch_bounds__(512, 4) void agg_kernel(const unsigned int* __restrict__ tmp,
                                                     const int* __restrict__ cursor_d,
                                                     const unsigned char* __restrict__ h8,
                                                     const unsigned short* __restrict__ h0b,
                                                     float* __restrict__ out) {
    __shared__ int es[CAP];        // 20480 B: within-block CSR edge srcs
    __shared__ int cnt[128];
    __shared__ int off[128];
    __shared__ int lc[128];
    __shared__ int sscan[128];

    int t = threadIdx.x;
    int b = blockIdx.x;

    if (t < 128) { cnt[t] = 0; lc[t] = 0; }
    __syncthreads();

    int nE = cursor_d[b];
    if (nE > CAP) nE = CAP;
    const unsigned int* te = tmp + (size_t)b * CAP;

    // pass 1: in-degree histogram (int LDS atomics)
    for (int e = t; e < nE; e += 512)
        atomicAdd(&cnt[te[e] >> 24], 1);
    __syncthreads();

    // exclusive prefix scan over 128 counters
    if (t < 128) sscan[t] = cnt[t];
    __syncthreads();
    #pragma unroll
    for (int o = 1; o < 128; o <<= 1) {
        int add = (t < 128 && t >= o) ? sscan[t - o] : 0;
        __syncthreads();
        if (t < 128) sscan[t] += add;
        __syncthreads();
    }
    if (t < 128) off[t] = sscan[t] - cnt[t];
    __syncthreads();

    // pass 2: scatter edge srcs into LDS CSR
    for (int e = t; e < nE; e += 512) {
        unsigned int v = te[e];
        int dl = v >> 24;
        int p = atomicAdd(&lc[dl], 1);
        es[off[dl] + p] = (int)(v & 0xFFFFFFu);
    }
    __syncthreads();

    // per-wave register-accumulating gather: wave w owns nodes [16w, 16w+16)
    int w    = t >> 6;
    int lane = t & 63;
    int half = lane >> 5;          // edge slot parity
    int c2   = lane & 31;          // channel pair (c2, c2+32)
    const unsigned short* h8p = reinterpret_cast<const unsigned short*>(h8); // row stride 32

    for (int r = 0; r < 16; ++r) {
        int nl   = (w << 4) + r;
        int node = (b << 7) + nl;
        int beg  = off[nl];
        int deg  = cnt[nl];
        int end  = beg + deg;
        float ax = 0.f, ay = 0.f;

        int base = beg;
        for (; base + 16 <= end; base += 16) {
            int e0 = base + half;
            int s0 = es[e0 +  0];
            int s1 = es[e0 +  2];
            int s2 = es[e0 +  4];
            int s3 = es[e0 +  6];
            int s4 = es[e0 +  8];
            int s5 = es[e0 + 10];
            int s6 = es[e0 + 12];
            int s7 = es[e0 + 14];
            unsigned short u0 = h8p[s0 * 32 + c2];
            unsigned short u1 = h8p[s1 * 32 + c2];
            unsigned short u2 = h8p[s2 * 32 + c2];
            unsigned short u3 = h8p[s3 * 32 + c2];
            unsigned short u4 = h8p[s4 * 32 + c2];
            unsigned short u5 = h8p[s5 * 32 + c2];
            unsigned short u6 = h8p[s6 * 32 + c2];
            unsigned short u7 = h8p[s7 * 32 + c2];
            f32x2 f0 = fp8x2_to_f32(u0);
            f32x2 f1 = fp8x2_to_f32(u1);
            f32x2 f2 = fp8x2_to_f32(u2);
            f32x2 f3 = fp8x2_to_f32(u3);
            f32x2 f4 = fp8x2_to_f32(u4);
            f32x2 f5 = fp8x2_to_f32(u5);
            f32x2 f6 = fp8x2_to_f32(u6);
            f32x2 f7 = fp8x2_to_f32(u7);
            ax += (f0[0] + f1[0]) + (f2[0] + f3[0]) + (f4[0] + f5[0]) + (f6[0] + f7[0]);
            ay += (f0[1] + f1[1]) + (f2[1] + f3[1]) + (f4[1] + f5[1]) + (f6[1] + f7[1]);
        }
        for (int e = base + half; e < end; e += 2) {
            int s = es[e];
            f32x2 f = fp8x2_to_f32(h8p[s * 32 + c2]);
            ax += f[0];
            ay += f[1];
        }

        ax += __shfl(ax, lane ^ 32, 64);
        ay += __shfl(ay, lane ^ 32, 64);

        if (half == 0 && node < N_NODES) {
            float nd = rsqrtf((float)(deg < 1 ? 1 : deg));
            float hx = bf2f(h0b[(size_t)node * C_OUT + c2]);
            float hy = bf2f(h0b[(size_t)node * C_OUT + c2 + 32]);
            out[(size_t)node * C_OUT + c2]      = 0.8f * nd * ax + 0.2f * hx;
            out[(size_t)node * C_OUT + c2 + 32] = 0.8f * nd * ay + 0.2f * hy;
        }
    }
}

// ---------------------------------------------------------------------------
extern "C" void kernel_launch(void* const* d_in, const int* in_sizes, int n_in,
                              void* d_out, int out_size, void* d_ws, size_t ws_size,
                              hipStream_t stream) {
    const float* in_feat = (const float*)d_in[0];   // [N, 512]
    const float* W       = (const float*)d_in[1];   // [64, 512]
    const float* bias    = (const float*)d_in[2];   // [64]
    const int*   src     = (const int*)d_in[3];     // [E]
    const int*   dst     = (const int*)d_in[4];     // [E]
    float* out = (float*)d_out;                     // [N, 64]

    // workspace layout (no aliasing; ~36MB of ~800MB):
    char* p = (char*)d_ws;
    unsigned short* h0b = (unsigned short*)p;  p += (size_t)N_NODES * C_OUT * 2;   // 12.8MB
    unsigned char*  h8  = (unsigned char*)p;   p += (size_t)N_NODES * C_OUT;       // 6.4MB
    unsigned int*   tmp = (unsigned int*)p;    p += (size_t)NB * CAP * 4;          // 16MB
    int*   deg_src  = (int*)p;                 p += (size_t)N_NODES * 4;           // 0.4MB
    int*   cursor_d = (int*)p;                 p += (size_t)NB * 4;
    unsigned short* Wb = (unsigned short*)p;   p += (size_t)C_OUT * F_IN * 2;      // 64KB

    zero_kernel<<<(N_NODES + 511) / 512, 512, 0, stream>>>(W, Wb, deg_src, cursor_d);
    p2_part<<<NTILE, 512, 0, stream>>>(src, dst, cursor_d, deg_src, tmp);
    gemm_kernel<<<(N_NODES + 255) / 256, 512, 0, stream>>>(in_feat, Wb, bias,
                                                           deg_src, h0b, h8);
    agg_kernel<<<NB, 512, 0, stream>>>(tmp, cursor_d, h8, h0b, out);
}